// Round 5
// baseline (5414.140 us; speedup 1.0000x reference)
//
#include <hip/hip_runtime.h>
#include <hip/hip_bf16.h>

// ---------------- geometry (ViT-B/16 + VPT, hard-coded by reference) --------
#define B_   32
#define S_   213     // 197 base tokens + 16 prompts
#define NP_  197
#define P_   16
#define E_   768
#define H_   12
#define HD_  64
#define FF_  3072
#define L_   12
#define EPS_ 1e-6f
#define SCALE_ 0.125f   // 1/sqrt(64)

typedef __attribute__((ext_vector_type(8))) short short8;
typedef __attribute__((ext_vector_type(4))) float floatx4;

__device__ __forceinline__ ushort f2b(float x) {
  __hip_bfloat16 h = __float2bfloat16(x);
  return __builtin_bit_cast(ushort, h);
}
__device__ __forceinline__ float b2f(ushort u) {
  return __uint_as_float(((unsigned)u) << 16);
}

__device__ __forceinline__ void glds16(const void* g, void* l) {
  __builtin_amdgcn_global_load_lds(
      (const __attribute__((address_space(1))) void*)g,
      (__attribute__((address_space(3))) void*)l, 16, 0, 0);
}

// ---------------------------------------------------------------------------
// bf16 MFMA NT GEMM: C[m,n] = sum_k A[m,k] * W[n,k] + bias[n]
// 128x128 tile, BK=32, 256 thr (4 waves, each 64x64 via 4x4 mfma_16x16x32).
// Single-buffer two-barrier K-loop (round-3 proven; explicit pipelining was
// neutral per round-4 counters -- compiler re-inserts its own waitcnts).
// MODE 0: bf16 store               MODE 1: exact GELU -> bf16
// MODE 3: qkv split (q,k row-stride 1536; v -> vt[b,h][kc][d][8])
// MODE 4: split-K partial, fp32 atomicAdd into Cf (residual accumulates);
//         bias added only by slice blockIdx.z==0. Ks = full row stride,
//         Kl = this slice's K length (slice offset = blockIdx.z * Kl).
// ---------------------------------------------------------------------------
template <int MODE>
__global__ __launch_bounds__(256) void gemm_mfma(
    const ushort* __restrict__ A, const ushort* __restrict__ W,
    const float* __restrict__ bias, float* __restrict__ Cf,
    ushort* __restrict__ Cb, ushort* __restrict__ Vout,
    int M, int N, int Ks, int Kl) {
  __shared__ alignas(16) ushort Al[4096];
  __shared__ alignas(16) ushort Wl[4096];
  const int tid = threadIdx.x;
  const int w = tid >> 6, l = tid & 63;
  const int m0 = blockIdx.y * 128, n0 = blockIdx.x * 128;
  const int rw = (w >> 1) * 64, cw = (w & 1) * 64;
  const int koff = blockIdx.z * Kl;

  const int mA0 = min(m0 + l, M - 1);
  const int mA1 = min(m0 + 64 + l, M - 1);
  const ushort* Ag0 = A + (size_t)mA0 * Ks + koff + w * 8;
  const ushort* Ag1 = A + (size_t)mA1 * Ks + koff + w * 8;
  const ushort* Wg0 = W + (size_t)(n0 + l) * Ks + koff + w * 8;
  const ushort* Wg1 = W + (size_t)(n0 + 64 + l) * Ks + koff + w * 8;
  ushort* Ald0 = &Al[w * 1024];
  ushort* Ald1 = &Al[w * 1024 + 512];
  ushort* Wld0 = &Wl[w * 1024];
  ushort* Wld1 = &Wl[w * 1024 + 512];

  floatx4 acc[4][4];
#pragma unroll
  for (int i = 0; i < 4; ++i)
#pragma unroll
    for (int j = 0; j < 4; ++j) acc[i][j] = (floatx4){0.f, 0.f, 0.f, 0.f};

  const int lm = l & 15, lk = l >> 4;

  for (int k0 = 0; k0 < Kl; k0 += 32) {
    glds16(Ag0 + k0, Ald0);
    glds16(Ag1 + k0, Ald1);
    glds16(Wg0 + k0, Wld0);
    glds16(Wg1 + k0, Wld1);
    __syncthreads();
    short8 af[4], bf[4];
#pragma unroll
    for (int s = 0; s < 4; ++s) {
      af[s] = *(const short8*)&Al[(size_t)(lk * 128 + rw + s * 16 + lm) * 8];
      bf[s] = *(const short8*)&Wl[(size_t)(lk * 128 + cw + s * 16 + lm) * 8];
    }
#pragma unroll
    for (int i = 0; i < 4; ++i)
#pragma unroll
      for (int j = 0; j < 4; ++j)
        acc[i][j] = __builtin_amdgcn_mfma_f32_16x16x32_bf16(
            af[i], bf[j], acc[i][j], 0, 0, 0);
    __syncthreads();
  }

  const int lq = l >> 4;
#pragma unroll
  for (int i = 0; i < 4; ++i) {
    const int row0 = m0 + rw + i * 16 + lq * 4;
#pragma unroll
    for (int j = 0; j < 4; ++j) {
      const int col = n0 + cw + j * 16 + lm;
      const float bc = (MODE == 4 && blockIdx.z != 0) ? 0.f : bias[col];
#pragma unroll
      for (int r = 0; r < 4; ++r) {
        const int row = row0 + r;
        if (row >= M) continue;
        float v = acc[i][j][r] + bc;
        if (MODE == 0) Cb[(size_t)row * N + col] = f2b(v);
        if (MODE == 1) {
          v = 0.5f * v * (1.0f + erff(v * 0.70710678118654752f));
          Cb[(size_t)row * N + col] = f2b(v);
        }
        if (MODE == 3) {
          if (col < 1536) {
            Cb[(size_t)row * 1536 + col] = f2b(v);
          } else {
            const int c = col - 1536, hh = c >> 6, dd = c & 63;
            const int bb = row / 213, ss = row % 213;
            Vout[(((size_t)(bb * 12 + hh) * 28 + (ss >> 3)) * 64 + dd) * 8 +
                 (ss & 7)] = f2b(v);
          }
        }
        if (MODE == 4) atomicAdd(&Cf[(size_t)row * N + col], v);
      }
    }
  }
}

// ---------------------------------------------------------------------------
// Patch-embed MFMA GEMM with on-the-fly im2col. M=6272, N=768, K=768.
// ---------------------------------------------------------------------------
__global__ __launch_bounds__(256) void patch_mfma(
    const ushort* __restrict__ xb, const ushort* __restrict__ pwb,
    const float* __restrict__ pb, const float* __restrict__ pos,
    float* __restrict__ xc) {
  __shared__ alignas(16) ushort Al[4096];
  __shared__ alignas(16) ushort Wl[4096];
  const int tid = threadIdx.x;
  const int w = tid >> 6, l = tid & 63;
  const int m0 = blockIdx.y * 128, n0 = blockIdx.x * 128;
  const int rw = (w >> 1) * 64, cw = (w & 1) * 64;

  const int mA0 = m0 + l, mA1 = m0 + 64 + l;
  const int b0 = mA0 / 196, p0 = mA0 % 196, pr0 = p0 / 14, pc0 = p0 % 14;
  const int b1 = mA1 / 196, p1 = mA1 % 196, pr1 = p1 / 14, pc1 = p1 % 14;
  const ushort* Wg0 = pwb + (size_t)(n0 + l) * 768 + w * 8;
  const ushort* Wg1 = pwb + (size_t)(n0 + 64 + l) * 768 + w * 8;
  ushort* Ald0 = &Al[w * 1024];
  ushort* Ald1 = &Al[w * 1024 + 512];
  ushort* Wld0 = &Wl[w * 1024];
  ushort* Wld1 = &Wl[w * 1024 + 512];

  floatx4 acc[4][4];
#pragma unroll
  for (int i = 0; i < 4; ++i)
#pragma unroll
    for (int j = 0; j < 4; ++j) acc[i][j] = (floatx4){0.f, 0.f, 0.f, 0.f};

  const int lm = l & 15, lk = l >> 4;

  for (int k0 = 0; k0 < 768; k0 += 32) {
    const int k = k0 + w * 8;
    const int c = k >> 8, kh = (k >> 4) & 15, kw = k & 15;
    const ushort* a0 =
        xb + ((size_t)(b0 * 3 + c) * 224 + pr0 * 16 + kh) * 224 + pc0 * 16 + kw;
    const ushort* a1 =
        xb + ((size_t)(b1 * 3 + c) * 224 + pr1 * 16 + kh) * 224 + pc1 * 16 + kw;
    glds16(a0, Ald0);
    glds16(a1, Ald1);
    glds16(Wg0 + k0, Wld0);
    glds16(Wg1 + k0, Wld1);
    __syncthreads();
    short8 af[4], bf[4];
#pragma unroll
    for (int s = 0; s < 4; ++s) {
      af[s] = *(const short8*)&Al[(size_t)(lk * 128 + rw + s * 16 + lm) * 8];
      bf[s] = *(const short8*)&Wl[(size_t)(lk * 128 + cw + s * 16 + lm) * 8];
    }
#pragma unroll
    for (int i = 0; i < 4; ++i)
#pragma unroll
      for (int j = 0; j < 4; ++j)
        acc[i][j] = __builtin_amdgcn_mfma_f32_16x16x32_bf16(
            af[i], bf[j], acc[i][j], 0, 0, 0);
    __syncthreads();
  }

  const int lq = l >> 4;
#pragma unroll
  for (int i = 0; i < 4; ++i) {
    const int row0 = m0 + rw + i * 16 + lq * 4;
#pragma unroll
    for (int j = 0; j < 4; ++j) {
      const int col = n0 + cw + j * 16 + lm;
      const float bc = pb[col];
#pragma unroll
      for (int r = 0; r < 4; ++r) {
        const int row = row0 + r;
        const int bb = row / 196, pp = row % 196, t = pp + 1;
        xc[((size_t)bb * S_ + t) * E_ + col] =
            acc[i][j][r] + bc + pos[(size_t)t * E_ + col];
      }
    }
  }
}

// ---------------------------------------------------------------------------
// fp32 -> bf16 converters
// ---------------------------------------------------------------------------
__global__ __launch_bounds__(256) void conv_x_kernel(
    const float* __restrict__ x, const float* __restrict__ pw,
    ushort* __restrict__ xb, ushort* __restrict__ pwb) {
  size_t t = (size_t)blockIdx.x * 256 + threadIdx.x;
  const float4* s;
  ushort* d;
  size_t off;
  if (t < 1204224) { s = (const float4*)x;  d = xb;  off = t; }
  else             { s = (const float4*)pw; d = pwb; off = t - 1204224; }
  float4 v = s[off];
  ushort4 r;
  r.x = f2b(v.x); r.y = f2b(v.y); r.z = f2b(v.z); r.w = f2b(v.w);
  *(ushort4*)(d + off * 4) = r;
}

__global__ __launch_bounds__(256) void conv_w_kernel(
    const float* __restrict__ qkvw, const float* __restrict__ projw,
    const float* __restrict__ f1w, const float* __restrict__ f2w,
    ushort* __restrict__ wq, ushort* __restrict__ wp,
    ushort* __restrict__ w1, ushort* __restrict__ w2) {
  size_t t = (size_t)blockIdx.x * 256 + threadIdx.x;
  const float4* s;
  ushort* d;
  size_t off;
  if (t < 442368)       { s = (const float4*)qkvw; d = wq; off = t; }
  else if (t < 589824)  { s = (const float4*)projw; d = wp; off = t - 442368; }
  else if (t < 1179648) { s = (const float4*)f1w;  d = w1; off = t - 589824; }
  else                  { s = (const float4*)f2w;  d = w2; off = t - 1179648; }
  float4 v = s[off];
  ushort4 r;
  r.x = f2b(v.x); r.y = f2b(v.y); r.z = f2b(v.z); r.w = f2b(v.w);
  *(ushort4*)(d + off * 4) = r;
}

// zero the key-pad slots (s=213..223) of vt[b,h][kc][d][8]
__global__ __launch_bounds__(256) void vt_pad_zero(ushort* __restrict__ vt) {
  int idx = blockIdx.x * 256 + threadIdx.x;
  if (idx >= 384 * 64 * 11) return;
  int bh = idx / 704;
  int rem = idx % 704;
  int d = rem / 11, ee = rem % 11;
  int s = 213 + ee;
  vt[(((size_t)bh * 28 + (s >> 3)) * 64 + d) * 8 + (s & 7)] = 0;
}

// ---------------------------------------------------------------------------
__global__ __launch_bounds__(256) void init_cls_prompts(
    const float* __restrict__ cls, const float* __restrict__ pos,
    float* __restrict__ xc) {
  int idx = blockIdx.x;
  int b = idx / 17, s = idx % 17;
  int tid = threadIdx.x;
  if (s == 0) {
    for (int e = tid; e < E_; e += 256)
      xc[(size_t)b * S_ * E_ + e] = cls[e] + pos[e];
  } else {
    int t = 196 + s;
    for (int e = tid; e < E_; e += 256)
      xc[((size_t)b * S_ + t) * E_ + e] = 0.f;
  }
}

__device__ inline float2 block_sums(float s, float q) {
  __shared__ float sm[8];
#pragma unroll
  for (int off = 32; off; off >>= 1) {
    s += __shfl_xor(s, off);
    q += __shfl_xor(q, off);
  }
  int lane = threadIdx.x & 63, wid = threadIdx.x >> 6;
  if (lane == 0) { sm[2 * wid] = s; sm[2 * wid + 1] = q; }
  __syncthreads();
  float2 r;
  r.x = sm[0] + sm[2] + sm[4] + sm[6];
  r.y = sm[1] + sm[3] + sm[5] + sm[7];
  return r;
}

__global__ __launch_bounds__(256) void ln_pre_kernel(
    float* __restrict__ xc, const float* __restrict__ g,
    const float* __restrict__ bb) {
  int idx = blockIdx.x;
  int b = idx / NP_, t = idx % NP_;
  float* row = xc + ((size_t)b * S_ + t) * E_;
  int tid = threadIdx.x;
  float v0 = row[tid], v1 = row[tid + 256], v2 = row[tid + 512];
  float2 r = block_sums(v0 + v1 + v2, v0 * v0 + v1 * v1 + v2 * v2);
  float mean = r.x * (1.f / 768.f);
  float var  = r.y * (1.f / 768.f) - mean * mean;
  float rstd = rsqrtf(var + EPS_);
  row[tid]       = (v0 - mean) * rstd * g[tid]       + bb[tid];
  row[tid + 256] = (v1 - mean) * rstd * g[tid + 256] + bb[tid + 256];
  row[tid + 512] = (v2 - mean) * rstd * g[tid + 512] + bb[tid + 512];
}

__global__ __launch_bounds__(256) void ln_block_kernel(
    float* __restrict__ xc, ushort* __restrict__ hh,
    const float* __restrict__ g, const float* __restrict__ bb,
    const float* __restrict__ prompt) {
  int idx = blockIdx.x;
  int b = idx / S_, t = idx % S_;
  float* row = xc + ((size_t)b * S_ + t) * E_;
  ushort* orow = hh + ((size_t)b * S_ + t) * E_;
  int tid = threadIdx.x;
  float v0, v1, v2;
  if (prompt != nullptr && t >= NP_) {
    const float* pr = prompt + (size_t)(t - NP_) * E_;
    v0 = pr[tid]; v1 = pr[tid + 256]; v2 = pr[tid + 512];
    row[tid] = v0; row[tid + 256] = v1; row[tid + 512] = v2;
  } else {
    v0 = row[tid]; v1 = row[tid + 256]; v2 = row[tid + 512];
  }
  float2 r = block_sums(v0 + v1 + v2, v0 * v0 + v1 * v1 + v2 * v2);
  float mean = r.x * (1.f / 768.f);
  float var  = r.y * (1.f / 768.f) - mean * mean;
  float rstd = rsqrtf(var + EPS_);
  orow[tid]       = f2b((v0 - mean) * rstd * g[tid]       + bb[tid]);
  orow[tid + 256] = f2b((v1 - mean) * rstd * g[tid + 256] + bb[tid + 256]);
  orow[tid + 512] = f2b((v2 - mean) * rstd * g[tid + 512] + bb[tid + 512]);
}

__global__ __launch_bounds__(256) void ln_post_kernel(
    const float* __restrict__ xc, const float* __restrict__ g,
    const float* __restrict__ bb, float* __restrict__ out) {
  int b = blockIdx.x;
  const float* row = xc + (size_t)b * S_ * E_;
  int tid = threadIdx.x;
  float v0 = row[tid], v1 = row[tid + 256], v2 = row[tid + 512];
  float2 r = block_sums(v0 + v1 + v2, v0 * v0 + v1 * v1 + v2 * v2);
  float mean = r.x * (1.f / 768.f);
  float var  = r.y * (1.f / 768.f) - mean * mean;
  float rstd = rsqrtf(var + EPS_);
  out[(size_t)b * E_ + tid]       = (v0 - mean) * rstd * g[tid]       + bb[tid];
  out[(size_t)b * E_ + tid + 256] = (v1 - mean) * rstd * g[tid + 256] + bb[tid + 256];
  out[(size_t)b * E_ + tid + 512] = (v2 - mean) * rstd * g[tid + 512] + bb[tid + 512];
}

// ---------------------------------------------------------------------------
// MFMA attention. One block per (b,h); 4 waves; wave w owns q-tiles w,w+4,...
// ---------------------------------------------------------------------------
__global__ __launch_bounds__(256) void attn_mfma(
    const ushort* __restrict__ qk, const ushort* __restrict__ vt,
    const float* __restrict__ coeff, ushort* __restrict__ o) {
  __shared__ alignas(16) ushort Vts[14336];      // [kc 0..27][d 0..63][8]
  __shared__ alignas(16) ushort Pss[4][3808];    // [kc 0..27][q 0..16pad][8]
  const int bh = blockIdx.x, h = bh % H_, b = bh / H_;
  const int tid = threadIdx.x, w = tid >> 6, lane = tid & 63;
  const int lm = lane & 15, quad = lane >> 4;

  const ushort* vsrc = vt + (size_t)bh * 14336;
#pragma unroll
  for (int i = 0; i < 7; ++i) {
    const int idx = w * 64 + i * 256;
    glds16(vsrc + (size_t)(idx + lane) * 8, &Vts[idx * 8]);
  }
  __syncthreads();

  const ushort* qbase = qk + (size_t)b * S_ * 1536;
  const float f12 = (lm < 5) ? 1.f : coeff[lm - 5];     // keys 192..207
  const float f13 = (lm < 5) ? coeff[11 + lm] : 0.f;    // keys 208..212
  ushort* Pw = &Pss[w][0];

  for (int qt = w; qt < 14; qt += 4) {
    const int q0 = qt * 16;
    const int qrow = min(q0 + lm, 212);
    const ushort* qp = qbase + (size_t)qrow * 1536 + h * 64 + quad * 8;
    const short8 a0 = *(const short8*)(qp);
    const short8 a1 = *(const short8*)(qp + 32);

    floatx4 acc[14];
#pragma unroll
    for (int t = 0; t < 14; ++t) {
      const int krow = min(t * 16 + lm, 212);
      const ushort* kp = qbase + (size_t)krow * 1536 + 768 + h * 64 + quad * 8;
      const short8 b0 = *(const short8*)(kp);
      const short8 b1 = *(const short8*)(kp + 32);
      floatx4 c = __builtin_amdgcn_mfma_f32_16x16x32_bf16(
          a0, b0, (floatx4){0.f, 0.f, 0.f, 0.f}, 0, 0, 0);
      acc[t] = __builtin_amdgcn_mfma_f32_16x16x32_bf16(a1, b1, c, 0, 0, 0);
    }

    const int qi = quad * 4;
#pragma unroll
    for (int r = 0; r < 4; ++r) {
      float v[14];
#pragma unroll
      for (int t = 0; t < 14; ++t) {
        float s = acc[t][r] * SCALE_;
        if (t == 12) s *= f12;
        if (t == 13) s = (lm < 5) ? s * f13 : -1e30f;
        v[t] = s;
      }
      float mx = v[0];
#pragma unroll
      for (int t = 1; t < 14; ++t) mx = fmaxf(mx, v[t]);
      mx = fmaxf(mx, __shfl_xor(mx, 1));
      mx = fmaxf(mx, __shfl_xor(mx, 2));
      mx = fmaxf(mx, __shfl_xor(mx, 4));
      mx = fmaxf(mx, __shfl_xor(mx, 8));
      float sum = 0.f;
#pragma unroll
      for (int t = 0; t < 14; ++t) {
        float e = __expf(v[t] - mx);
        v[t] = e;
        sum += e;
      }
      sum += __shfl_xor(sum, 1);
      sum += __shfl_xor(sum, 2);
      sum += __shfl_xor(sum, 4);
      sum += __shfl_xor(sum, 8);
      const float inv = 1.f / sum;
#pragma unroll
      for (int t = 0; t < 14; ++t) {
        const int key = t * 16 + lm;
        Pw[((key >> 3) * 17 + qi + r) * 8 + (key & 7)] = f2b(v[t] * inv);
      }
    }

    short8 pa[7];
#pragma unroll
    for (int c = 0; c < 7; ++c)
      pa[c] = *(const short8*)&Pw[((c * 4 + quad) * 17 + lm) * 8];
#pragma unroll
    for (int nt = 0; nt < 4; ++nt) {
      floatx4 oa = (floatx4){0.f, 0.f, 0.f, 0.f};
#pragma unroll
      for (int c = 0; c < 7; ++c) {
        const short8 vb =
            *(const short8*)&Vts[((c * 4 + quad) * 64 + nt * 16 + lm) * 8];
        oa = __builtin_amdgcn_mfma_f32_16x16x32_bf16(pa[c], vb, oa, 0, 0, 0);
      }
#pragma unroll
      for (int r = 0; r < 4; ++r) {
        const int q = q0 + quad * 4 + r;
        if (q < S_)
          o[((size_t)b * S_ + q) * E_ + h * HD_ + nt * 16 + lm] = f2b(oa[r]);
      }
    }
  }
}

// ---------------------------------------------------------------------------
extern "C" void kernel_launch(void* const* d_in, const int* in_sizes, int n_in,
                              void* d_out, int out_size, void* d_ws,
                              size_t ws_size, hipStream_t stream) {
  const float* x         = (const float*)d_in[0];
  const float* cof       = (const float*)d_in[1];
  const float* patch_w   = (const float*)d_in[2];
  const float* patch_b   = (const float*)d_in[3];
  const float* cls       = (const float*)d_in[4];
  const float* pos       = (const float*)d_in[5];
  const float* ln_pre_g  = (const float*)d_in[6];
  const float* ln_pre_b  = (const float*)d_in[7];
  const float* prompts   = (const float*)d_in[8];
  const float* ln1_g     = (const float*)d_in[9];
  const float* ln1_b     = (const float*)d_in[10];
  const float* qkv_w     = (const float*)d_in[11];
  const float* qkv_b     = (const float*)d_in[12];
  const float* proj_w    = (const float*)d_in[13];
  const float* proj_b    = (const float*)d_in[14];
  const float* ln2_g     = (const float*)d_in[15];
  const float* ln2_b     = (const float*)d_in[16];
  const float* fc1_w     = (const float*)d_in[17];
  const float* fc1_b     = (const float*)d_in[18];
  const float* fc2_w     = (const float*)d_in[19];
  const float* fc2_b     = (const float*)d_in[20];
  const float* ln_post_g = (const float*)d_in[21];
  const float* ln_post_b = (const float*)d_in[22];
  float* out = (float*)d_out;

  // ws layout (~119.4 MB)
  float* xc  = (float*)d_ws;                // 5,234,688 f (fp32 residual)
  ushort* qk = (ushort*)(xc + 5234688);     // 10,469,376 us (q|k bf16)
  ushort* vt = qk + 10469376;               // 5,505,024 us (V^T chunked)
  ushort* hb = vt + 5505024;                // 5,234,688 us (LN-out / attn-out)
  ushort* fb = hb + 5234688;                // 20,938,752 us (fc1-out)
  ushort* wq = fb + 20938752;               // 1,769,472
  ushort* wp = wq + 1769472;                // 589,824
  ushort* w1 = wp + 589824;                 // 2,359,296
  ushort* w2 = w1 + 2359296;                // 2,359,296
  ushort* xb  = fb;   // alias: x bf16 (pre-layer0 only)
  ushort* pwb = qk;   // alias: patch_w bf16 (pre-layer0 only)

  const int M = B_ * S_;   // 6816
  const dim3 blk(256);

  conv_x_kernel<<<5280, blk, 0, stream>>>(x, patch_w, xb, pwb);
  patch_mfma<<<dim3(6, 49), blk, 0, stream>>>(xb, pwb, patch_b, pos, xc);
  init_cls_prompts<<<B_ * 17, blk, 0, stream>>>(cls, pos, xc);
  ln_pre_kernel<<<B_ * NP_, blk, 0, stream>>>(xc, ln_pre_g, ln_pre_b);
  vt_pad_zero<<<1056, blk, 0, stream>>>(vt);

  for (int l = 0; l < L_; ++l) {
    conv_w_kernel<<<6912, blk, 0, stream>>>(
        qkv_w + (size_t)l * 3 * E_ * E_, proj_w + (size_t)l * E_ * E_,
        fc1_w + (size_t)l * FF_ * E_, fc2_w + (size_t)l * E_ * FF_,
        wq, wp, w1, w2);
    ln_block_kernel<<<B_ * S_, blk, 0, stream>>>(
        xc, hb, ln1_g + l * E_, ln1_b + l * E_,
        prompts + (size_t)l * P_ * E_);
    gemm_mfma<3><<<dim3(18, 54), blk, 0, stream>>>(
        hb, wq, qkv_b + (size_t)l * 3 * E_, nullptr, qk, vt,
        M, 3 * E_, E_, E_);
    attn_mfma<<<B_ * H_, blk, 0, stream>>>(qk, vt, cof + (size_t)l * P_, hb);
    // proj: split-K=2 inside one dispatch (648 blocks), fp32 atomic residual
    gemm_mfma<4><<<dim3(6, 54, 2), blk, 0, stream>>>(
        hb, wp, proj_b + (size_t)l * E_, xc, nullptr, nullptr,
        M, E_, E_, E_ / 2);
    ln_block_kernel<<<B_ * S_, blk, 0, stream>>>(
        xc, hb, ln2_g + l * E_, ln2_b + l * E_, nullptr);
    gemm_mfma<1><<<dim3(24, 54), blk, 0, stream>>>(
        hb, w1, fc1_b + (size_t)l * FF_, nullptr, fb, nullptr,
        M, FF_, E_, E_);
    // fc2: split-K=4 inside one dispatch (1296 blocks)
    gemm_mfma<4><<<dim3(6, 54, 4), blk, 0, stream>>>(
        fb, w2, fc2_b + (size_t)l * E_, xc, nullptr, nullptr,
        M, E_, FF_, FF_ / 4);
  }

  ln_post_kernel<<<B_, blk, 0, stream>>>(xc, ln_post_g, ln_post_b, out);
}

// Round 6
// 5100.755 us; speedup vs baseline: 1.0614x; 1.0614x over previous
//
#include <hip/hip_runtime.h>
#include <hip/hip_bf16.h>

// ---------------- geometry (ViT-B/16 + VPT, hard-coded by reference) --------
#define B_   32
#define S_   213     // 197 base tokens + 16 prompts
#define NP_  197
#define P_   16
#define E_   768
#define H_   12
#define HD_  64
#define FF_  3072
#define L_   12
#define EPS_ 1e-6f
#define SCALE_ 0.125f   // 1/sqrt(64)

typedef __attribute__((ext_vector_type(8))) short short8;
typedef __attribute__((ext_vector_type(4))) float floatx4;

__device__ __forceinline__ ushort f2b(float x) {
  __hip_bfloat16 h = __float2bfloat16(x);
  return __builtin_bit_cast(ushort, h);
}
__device__ __forceinline__ float b2f(ushort u) {
  return __uint_as_float(((unsigned)u) << 16);
}

__device__ __forceinline__ void glds16(const void* g, void* l) {
  __builtin_amdgcn_global_load_lds(
      (const __attribute__((address_space(1))) void*)g,
      (__attribute__((address_space(3))) void*)l, 16, 0, 0);
}

// ---------------------------------------------------------------------------
// bf16 MFMA NT GEMM: C[m,n] = sum_k A[m,k] * W[n,k] + bias[n]
// 128x128 tile, BK=32, 256 thr (4 waves, each 64x64 via 4x4 mfma_16x16x32).
// Single-buffer two-barrier K-loop (round-3 proven; explicit pipelining and
// split-K both neutral/regressed per round-4/5 counters).
//
// XCD row-stripe swizzle: launched with gridDim.x == 8, so linear block id
// % 8 == blockIdx.x == XCD (HW round-robin). Each XCD owns complete row
// stripes (rows r = bx + 8*rowslot, ALL column tiles), so an A row-stripe is
// fetched into exactly one XCD's L2 instead of all eight. blockIdx.y
// enumerates (col, rowslot): col = by % GX, rowslot = by / GX.
// MODE 0: bf16 store               MODE 1: exact GELU -> bf16
// MODE 2: fp32 += (residual)
// MODE 3: qkv split (q,k row-stride 1536; v -> vt[b,h][kc][d][8])
// ---------------------------------------------------------------------------
template <int MODE>
__global__ __launch_bounds__(256) void gemm_mfma(
    const ushort* __restrict__ A, const ushort* __restrict__ W,
    const float* __restrict__ bias, float* __restrict__ Cf,
    ushort* __restrict__ Cb, ushort* __restrict__ Vout,
    int M, int N, int K) {
  const int GX = N >> 7;
  const int col = blockIdx.y % GX;
  const int r   = blockIdx.x + 8 * (blockIdx.y / GX);
  const int m0 = r * 128, n0 = col * 128;
  if (m0 >= M) return;

  __shared__ alignas(16) ushort Al[4096];
  __shared__ alignas(16) ushort Wl[4096];
  const int tid = threadIdx.x;
  const int w = tid >> 6, l = tid & 63;
  const int rw = (w >> 1) * 64, cw = (w & 1) * 64;

  const int mA0 = min(m0 + l, M - 1);
  const int mA1 = min(m0 + 64 + l, M - 1);
  const ushort* Ag0 = A + (size_t)mA0 * K + w * 8;
  const ushort* Ag1 = A + (size_t)mA1 * K + w * 8;
  const ushort* Wg0 = W + (size_t)(n0 + l) * K + w * 8;
  const ushort* Wg1 = W + (size_t)(n0 + 64 + l) * K + w * 8;
  ushort* Ald0 = &Al[w * 1024];
  ushort* Ald1 = &Al[w * 1024 + 512];
  ushort* Wld0 = &Wl[w * 1024];
  ushort* Wld1 = &Wl[w * 1024 + 512];

  floatx4 acc[4][4];
#pragma unroll
  for (int i = 0; i < 4; ++i)
#pragma unroll
    for (int j = 0; j < 4; ++j) acc[i][j] = (floatx4){0.f, 0.f, 0.f, 0.f};

  const int lm = l & 15, lk = l >> 4;

  for (int k0 = 0; k0 < K; k0 += 32) {
    glds16(Ag0 + k0, Ald0);
    glds16(Ag1 + k0, Ald1);
    glds16(Wg0 + k0, Wld0);
    glds16(Wg1 + k0, Wld1);
    __syncthreads();
    short8 af[4], bf[4];
#pragma unroll
    for (int s = 0; s < 4; ++s) {
      af[s] = *(const short8*)&Al[(size_t)(lk * 128 + rw + s * 16 + lm) * 8];
      bf[s] = *(const short8*)&Wl[(size_t)(lk * 128 + cw + s * 16 + lm) * 8];
    }
#pragma unroll
    for (int i = 0; i < 4; ++i)
#pragma unroll
      for (int j = 0; j < 4; ++j)
        acc[i][j] = __builtin_amdgcn_mfma_f32_16x16x32_bf16(
            af[i], bf[j], acc[i][j], 0, 0, 0);
    __syncthreads();
  }

  const int lq = l >> 4;
#pragma unroll
  for (int i = 0; i < 4; ++i) {
    const int row0 = m0 + rw + i * 16 + lq * 4;
#pragma unroll
    for (int j = 0; j < 4; ++j) {
      const int col2 = n0 + cw + j * 16 + lm;
      const float bc = bias[col2];
#pragma unroll
      for (int rr = 0; rr < 4; ++rr) {
        const int row = row0 + rr;
        if (row >= M) continue;
        float v = acc[i][j][rr] + bc;
        if (MODE == 0) Cb[(size_t)row * N + col2] = f2b(v);
        if (MODE == 1) {
          v = 0.5f * v * (1.0f + erff(v * 0.70710678118654752f));
          Cb[(size_t)row * N + col2] = f2b(v);
        }
        if (MODE == 2) Cf[(size_t)row * N + col2] += v;
        if (MODE == 3) {
          if (col2 < 1536) {
            Cb[(size_t)row * 1536 + col2] = f2b(v);
          } else {
            const int c = col2 - 1536, hh = c >> 6, dd = c & 63;
            const int bb = row / 213, ss = row % 213;
            Vout[(((size_t)(bb * 12 + hh) * 28 + (ss >> 3)) * 64 + dd) * 8 +
                 (ss & 7)] = f2b(v);
          }
        }
      }
    }
  }
}

// ---------------------------------------------------------------------------
// Patch-embed MFMA GEMM with on-the-fly im2col. M=6272, N=768, K=768.
// ---------------------------------------------------------------------------
__global__ __launch_bounds__(256) void patch_mfma(
    const ushort* __restrict__ xb, const ushort* __restrict__ pwb,
    const float* __restrict__ pb, const float* __restrict__ pos,
    float* __restrict__ xc) {
  __shared__ alignas(16) ushort Al[4096];
  __shared__ alignas(16) ushort Wl[4096];
  const int tid = threadIdx.x;
  const int w = tid >> 6, l = tid & 63;
  const int m0 = blockIdx.y * 128, n0 = blockIdx.x * 128;
  const int rw = (w >> 1) * 64, cw = (w & 1) * 64;

  const int mA0 = m0 + l, mA1 = m0 + 64 + l;
  const int b0 = mA0 / 196, p0 = mA0 % 196, pr0 = p0 / 14, pc0 = p0 % 14;
  const int b1 = mA1 / 196, p1 = mA1 % 196, pr1 = p1 / 14, pc1 = p1 % 14;
  const ushort* Wg0 = pwb + (size_t)(n0 + l) * 768 + w * 8;
  const ushort* Wg1 = pwb + (size_t)(n0 + 64 + l) * 768 + w * 8;
  ushort* Ald0 = &Al[w * 1024];
  ushort* Ald1 = &Al[w * 1024 + 512];
  ushort* Wld0 = &Wl[w * 1024];
  ushort* Wld1 = &Wl[w * 1024 + 512];

  floatx4 acc[4][4];
#pragma unroll
  for (int i = 0; i < 4; ++i)
#pragma unroll
    for (int j = 0; j < 4; ++j) acc[i][j] = (floatx4){0.f, 0.f, 0.f, 0.f};

  const int lm = l & 15, lk = l >> 4;

  for (int k0 = 0; k0 < 768; k0 += 32) {
    const int k = k0 + w * 8;
    const int c = k >> 8, kh = (k >> 4) & 15, kw = k & 15;
    const ushort* a0 =
        xb + ((size_t)(b0 * 3 + c) * 224 + pr0 * 16 + kh) * 224 + pc0 * 16 + kw;
    const ushort* a1 =
        xb + ((size_t)(b1 * 3 + c) * 224 + pr1 * 16 + kh) * 224 + pc1 * 16 + kw;
    glds16(a0, Ald0);
    glds16(a1, Ald1);
    glds16(Wg0 + k0, Wld0);
    glds16(Wg1 + k0, Wld1);
    __syncthreads();
    short8 af[4], bf[4];
#pragma unroll
    for (int s = 0; s < 4; ++s) {
      af[s] = *(const short8*)&Al[(size_t)(lk * 128 + rw + s * 16 + lm) * 8];
      bf[s] = *(const short8*)&Wl[(size_t)(lk * 128 + cw + s * 16 + lm) * 8];
    }
#pragma unroll
    for (int i = 0; i < 4; ++i)
#pragma unroll
      for (int j = 0; j < 4; ++j)
        acc[i][j] = __builtin_amdgcn_mfma_f32_16x16x32_bf16(
            af[i], bf[j], acc[i][j], 0, 0, 0);
    __syncthreads();
  }

  const int lq = l >> 4;
#pragma unroll
  for (int i = 0; i < 4; ++i) {
    const int row0 = m0 + rw + i * 16 + lq * 4;
#pragma unroll
    for (int j = 0; j < 4; ++j) {
      const int col = n0 + cw + j * 16 + lm;
      const float bc = pb[col];
#pragma unroll
      for (int r = 0; r < 4; ++r) {
        const int row = row0 + r;
        const int bb = row / 196, pp = row % 196, t = pp + 1;
        xc[((size_t)bb * S_ + t) * E_ + col] =
            acc[i][j][r] + bc + pos[(size_t)t * E_ + col];
      }
    }
  }
}

// ---------------------------------------------------------------------------
// fp32 -> bf16 converters
// ---------------------------------------------------------------------------
__global__ __launch_bounds__(256) void conv_x_kernel(
    const float* __restrict__ x, const float* __restrict__ pw,
    ushort* __restrict__ xb, ushort* __restrict__ pwb) {
  size_t t = (size_t)blockIdx.x * 256 + threadIdx.x;
  const float4* s;
  ushort* d;
  size_t off;
  if (t < 1204224) { s = (const float4*)x;  d = xb;  off = t; }
  else             { s = (const float4*)pw; d = pwb; off = t - 1204224; }
  float4 v = s[off];
  ushort4 r;
  r.x = f2b(v.x); r.y = f2b(v.y); r.z = f2b(v.z); r.w = f2b(v.w);
  *(ushort4*)(d + off * 4) = r;
}

__global__ __launch_bounds__(256) void conv_w_kernel(
    const float* __restrict__ qkvw, const float* __restrict__ projw,
    const float* __restrict__ f1w, const float* __restrict__ f2w,
    ushort* __restrict__ wq, ushort* __restrict__ wp,
    ushort* __restrict__ w1, ushort* __restrict__ w2) {
  size_t t = (size_t)blockIdx.x * 256 + threadIdx.x;
  const float4* s;
  ushort* d;
  size_t off;
  if (t < 442368)       { s = (const float4*)qkvw; d = wq; off = t; }
  else if (t < 589824)  { s = (const float4*)projw; d = wp; off = t - 442368; }
  else if (t < 1179648) { s = (const float4*)f1w;  d = w1; off = t - 589824; }
  else                  { s = (const float4*)f2w;  d = w2; off = t - 1179648; }
  float4 v = s[off];
  ushort4 r;
  r.x = f2b(v.x); r.y = f2b(v.y); r.z = f2b(v.z); r.w = f2b(v.w);
  *(ushort4*)(d + off * 4) = r;
}

// zero the key-pad slots (s=213..223) of vt[b,h][kc][d][8]
__global__ __launch_bounds__(256) void vt_pad_zero(ushort* __restrict__ vt) {
  int idx = blockIdx.x * 256 + threadIdx.x;
  if (idx >= 384 * 64 * 11) return;
  int bh = idx / 704;
  int rem = idx % 704;
  int d = rem / 11, ee = rem % 11;
  int s = 213 + ee;
  vt[(((size_t)bh * 28 + (s >> 3)) * 64 + d) * 8 + (s & 7)] = 0;
}

// ---------------------------------------------------------------------------
__global__ __launch_bounds__(256) void init_cls_prompts(
    const float* __restrict__ cls, const float* __restrict__ pos,
    float* __restrict__ xc) {
  int idx = blockIdx.x;
  int b = idx / 17, s = idx % 17;
  int tid = threadIdx.x;
  if (s == 0) {
    for (int e = tid; e < E_; e += 256)
      xc[(size_t)b * S_ * E_ + e] = cls[e] + pos[e];
  } else {
    int t = 196 + s;
    for (int e = tid; e < E_; e += 256)
      xc[((size_t)b * S_ + t) * E_ + e] = 0.f;
  }
}

__device__ inline float2 block_sums(float s, float q) {
  __shared__ float sm[8];
#pragma unroll
  for (int off = 32; off; off >>= 1) {
    s += __shfl_xor(s, off);
    q += __shfl_xor(q, off);
  }
  int lane = threadIdx.x & 63, wid = threadIdx.x >> 6;
  if (lane == 0) { sm[2 * wid] = s; sm[2 * wid + 1] = q; }
  __syncthreads();
  float2 r;
  r.x = sm[0] + sm[2] + sm[4] + sm[6];
  r.y = sm[1] + sm[3] + sm[5] + sm[7];
  return r;
}

__global__ __launch_bounds__(256) void ln_pre_kernel(
    float* __restrict__ xc, const float* __restrict__ g,
    const float* __restrict__ bb) {
  int idx = blockIdx.x;
  int b = idx / NP_, t = idx % NP_;
  float* row = xc + ((size_t)b * S_ + t) * E_;
  int tid = threadIdx.x;
  float v0 = row[tid], v1 = row[tid + 256], v2 = row[tid + 512];
  float2 r = block_sums(v0 + v1 + v2, v0 * v0 + v1 * v1 + v2 * v2);
  float mean = r.x * (1.f / 768.f);
  float var  = r.y * (1.f / 768.f) - mean * mean;
  float rstd = rsqrtf(var + EPS_);
  row[tid]       = (v0 - mean) * rstd * g[tid]       + bb[tid];
  row[tid + 256] = (v1 - mean) * rstd * g[tid + 256] + bb[tid + 256];
  row[tid + 512] = (v2 - mean) * rstd * g[tid + 512] + bb[tid + 512];
}

__global__ __launch_bounds__(256) void ln_block_kernel(
    float* __restrict__ xc, ushort* __restrict__ hh,
    const float* __restrict__ g, const float* __restrict__ bb,
    const float* __restrict__ prompt) {
  int idx = blockIdx.x;
  int b = idx / S_, t = idx % S_;
  float* row = xc + ((size_t)b * S_ + t) * E_;
  ushort* orow = hh + ((size_t)b * S_ + t) * E_;
  int tid = threadIdx.x;
  float v0, v1, v2;
  if (prompt != nullptr && t >= NP_) {
    const float* pr = prompt + (size_t)(t - NP_) * E_;
    v0 = pr[tid]; v1 = pr[tid + 256]; v2 = pr[tid + 512];
    row[tid] = v0; row[tid + 256] = v1; row[tid + 512] = v2;
  } else {
    v0 = row[tid]; v1 = row[tid + 256]; v2 = row[tid + 512];
  }
  float2 r = block_sums(v0 + v1 + v2, v0 * v0 + v1 * v1 + v2 * v2);
  float mean = r.x * (1.f / 768.f);
  float var  = r.y * (1.f / 768.f) - mean * mean;
  float rstd = rsqrtf(var + EPS_);
  orow[tid]       = f2b((v0 - mean) * rstd * g[tid]       + bb[tid]);
  orow[tid + 256] = f2b((v1 - mean) * rstd * g[tid + 256] + bb[tid + 256]);
  orow[tid + 512] = f2b((v2 - mean) * rstd * g[tid + 512] + bb[tid + 512]);
}

__global__ __launch_bounds__(256) void ln_post_kernel(
    const float* __restrict__ xc, const float* __restrict__ g,
    const float* __restrict__ bb, float* __restrict__ out) {
  int b = blockIdx.x;
  const float* row = xc + (size_t)b * S_ * E_;
  int tid = threadIdx.x;
  float v0 = row[tid], v1 = row[tid + 256], v2 = row[tid + 512];
  float2 r = block_sums(v0 + v1 + v2, v0 * v0 + v1 * v1 + v2 * v2);
  float mean = r.x * (1.f / 768.f);
  float var  = r.y * (1.f / 768.f) - mean * mean;
  float rstd = rsqrtf(var + EPS_);
  out[(size_t)b * E_ + tid]       = (v0 - mean) * rstd * g[tid]       + bb[tid];
  out[(size_t)b * E_ + tid + 256] = (v1 - mean) * rstd * g[tid + 256] + bb[tid + 256];
  out[(size_t)b * E_ + tid + 512] = (v2 - mean) * rstd * g[tid + 512] + bb[tid + 512];
}

// ---------------------------------------------------------------------------
// MFMA attention. One block per (b,h); 4 waves; wave w owns q-tiles w,w+4,...
// ---------------------------------------------------------------------------
__global__ __launch_bounds__(256) void attn_mfma(
    const ushort* __restrict__ qk, const ushort* __restrict__ vt,
    const float* __restrict__ coeff, ushort* __restrict__ o) {
  __shared__ alignas(16) ushort Vts[14336];      // [kc 0..27][d 0..63][8]
  __shared__ alignas(16) ushort Pss[4][3808];    // [kc 0..27][q 0..16pad][8]
  const int bh = blockIdx.x, h = bh % H_, b = bh / H_;
  const int tid = threadIdx.x, w = tid >> 6, lane = tid & 63;
  const int lm = lane & 15, quad = lane >> 4;

  const ushort* vsrc = vt + (size_t)bh * 14336;
#pragma unroll
  for (int i = 0; i < 7; ++i) {
    const int idx = w * 64 + i * 256;
    glds16(vsrc + (size_t)(idx + lane) * 8, &Vts[idx * 8]);
  }
  __syncthreads();

  const ushort* qbase = qk + (size_t)b * S_ * 1536;
  const float f12 = (lm < 5) ? 1.f : coeff[lm - 5];     // keys 192..207
  const float f13 = (lm < 5) ? coeff[11 + lm] : 0.f;    // keys 208..212
  ushort* Pw = &Pss[w][0];

  for (int qt = w; qt < 14; qt += 4) {
    const int q0 = qt * 16;
    const int qrow = min(q0 + lm, 212);
    const ushort* qp = qbase + (size_t)qrow * 1536 + h * 64 + quad * 8;
    const short8 a0 = *(const short8*)(qp);
    const short8 a1 = *(const short8*)(qp + 32);

    floatx4 acc[14];
#pragma unroll
    for (int t = 0; t < 14; ++t) {
      const int krow = min(t * 16 + lm, 212);
      const ushort* kp = qbase + (size_t)krow * 1536 + 768 + h * 64 + quad * 8;
      const short8 b0 = *(const short8*)(kp);
      const short8 b1 = *(const short8*)(kp + 32);
      floatx4 c = __builtin_amdgcn_mfma_f32_16x16x32_bf16(
          a0, b0, (floatx4){0.f, 0.f, 0.f, 0.f}, 0, 0, 0);
      acc[t] = __builtin_amdgcn_mfma_f32_16x16x32_bf16(a1, b1, c, 0, 0, 0);
    }

    const int qi = quad * 4;
#pragma unroll
    for (int r = 0; r < 4; ++r) {
      float v[14];
#pragma unroll
      for (int t = 0; t < 14; ++t) {
        float s = acc[t][r] * SCALE_;
        if (t == 12) s *= f12;
        if (t == 13) s = (lm < 5) ? s * f13 : -1e30f;
        v[t] = s;
      }
      float mx = v[0];
#pragma unroll
      for (int t = 1; t < 14; ++t) mx = fmaxf(mx, v[t]);
      mx = fmaxf(mx, __shfl_xor(mx, 1));
      mx = fmaxf(mx, __shfl_xor(mx, 2));
      mx = fmaxf(mx, __shfl_xor(mx, 4));
      mx = fmaxf(mx, __shfl_xor(mx, 8));
      float sum = 0.f;
#pragma unroll
      for (int t = 0; t < 14; ++t) {
        float e = __expf(v[t] - mx);
        v[t] = e;
        sum += e;
      }
      sum += __shfl_xor(sum, 1);
      sum += __shfl_xor(sum, 2);
      sum += __shfl_xor(sum, 4);
      sum += __shfl_xor(sum, 8);
      const float inv = 1.f / sum;
#pragma unroll
      for (int t = 0; t < 14; ++t) {
        const int key = t * 16 + lm;
        Pw[((key >> 3) * 17 + qi + r) * 8 + (key & 7)] = f2b(v[t] * inv);
      }
    }

    short8 pa[7];
#pragma unroll
    for (int c = 0; c < 7; ++c)
      pa[c] = *(const short8*)&Pw[((c * 4 + quad) * 17 + lm) * 8];
#pragma unroll
    for (int nt = 0; nt < 4; ++nt) {
      floatx4 oa = (floatx4){0.f, 0.f, 0.f, 0.f};
#pragma unroll
      for (int c = 0; c < 7; ++c) {
        const short8 vb =
            *(const short8*)&Vts[((c * 4 + quad) * 64 + nt * 16 + lm) * 8];
        oa = __builtin_amdgcn_mfma_f32_16x16x32_bf16(pa[c], vb, oa, 0, 0, 0);
      }
#pragma unroll
      for (int r = 0; r < 4; ++r) {
        const int q = q0 + quad * 4 + r;
        if (q < S_)
          o[((size_t)b * S_ + q) * E_ + h * HD_ + nt * 16 + lm] = f2b(oa[r]);
      }
    }
  }
}

// ---------------------------------------------------------------------------
extern "C" void kernel_launch(void* const* d_in, const int* in_sizes, int n_in,
                              void* d_out, int out_size, void* d_ws,
                              size_t ws_size, hipStream_t stream) {
  const float* x         = (const float*)d_in[0];
  const float* cof       = (const float*)d_in[1];
  const float* patch_w   = (const float*)d_in[2];
  const float* patch_b   = (const float*)d_in[3];
  const float* cls       = (const float*)d_in[4];
  const float* pos       = (const float*)d_in[5];
  const float* ln_pre_g  = (const float*)d_in[6];
  const float* ln_pre_b  = (const float*)d_in[7];
  const float* prompts   = (const float*)d_in[8];
  const float* ln1_g     = (const float*)d_in[9];
  const float* ln1_b     = (const float*)d_in[10];
  const float* qkv_w     = (const float*)d_in[11];
  const float* qkv_b     = (const float*)d_in[12];
  const float* proj_w    = (const float*)d_in[13];
  const float* proj_b    = (const float*)d_in[14];
  const float* ln2_g     = (const float*)d_in[15];
  const float* ln2_b     = (const float*)d_in[16];
  const float* fc1_w     = (const float*)d_in[17];
  const float* fc1_b     = (const float*)d_in[18];
  const float* fc2_w     = (const float*)d_in[19];
  const float* fc2_b     = (const float*)d_in[20];
  const float* ln_post_g = (const float*)d_in[21];
  const float* ln_post_b = (const float*)d_in[22];
  float* out = (float*)d_out;

  // ws layout (~119.4 MB)
  float* xc  = (float*)d_ws;                // 5,234,688 f (fp32 residual)
  ushort* qk = (ushort*)(xc + 5234688);     // 10,469,376 us (q|k bf16)
  ushort* vt = qk + 10469376;               // 5,505,024 us (V^T chunked)
  ushort* hb = vt + 5505024;                // 5,234,688 us (LN-out / attn-out)
  ushort* fb = hb + 5234688;                // 20,938,752 us (fc1-out)
  ushort* wq = fb + 20938752;               // 1,769,472
  ushort* wp = wq + 1769472;                // 589,824
  ushort* w1 = wp + 589824;                 // 2,359,296
  ushort* w2 = w1 + 2359296;                // 2,359,296
  ushort* xb  = fb;   // alias: x bf16 (pre-layer0 only)
  ushort* pwb = qk;   // alias: patch_w bf16 (pre-layer0 only)

  const int M = B_ * S_;   // 6816 -> 54 row-groups of 128
  const dim3 blk(256);
  // swizzled grids: gridDim.x = 8 (XCD), gridDim.y = GX * 7 rowslots
  const dim3 g_qkv(8, 18 * 7);   // N=2304
  const dim3 g_p76(8, 6 * 7);    // N=768 (proj, fc2)
  const dim3 g_fc1(8, 24 * 7);   // N=3072

  conv_x_kernel<<<5280, blk, 0, stream>>>(x, patch_w, xb, pwb);
  patch_mfma<<<dim3(6, 49), blk, 0, stream>>>(xb, pwb, patch_b, pos, xc);
  init_cls_prompts<<<B_ * 17, blk, 0, stream>>>(cls, pos, xc);
  ln_pre_kernel<<<B_ * NP_, blk, 0, stream>>>(xc, ln_pre_g, ln_pre_b);
  vt_pad_zero<<<1056, blk, 0, stream>>>(vt);

  for (int l = 0; l < L_; ++l) {
    conv_w_kernel<<<6912, blk, 0, stream>>>(
        qkv_w + (size_t)l * 3 * E_ * E_, proj_w + (size_t)l * E_ * E_,
        fc1_w + (size_t)l * FF_ * E_, fc2_w + (size_t)l * E_ * FF_,
        wq, wp, w1, w2);
    ln_block_kernel<<<B_ * S_, blk, 0, stream>>>(
        xc, hb, ln1_g + l * E_, ln1_b + l * E_,
        prompts + (size_t)l * P_ * E_);
    gemm_mfma<3><<<g_qkv, blk, 0, stream>>>(
        hb, wq, qkv_b + (size_t)l * 3 * E_, nullptr, qk, vt, M, 3 * E_, E_);
    attn_mfma<<<B_ * H_, blk, 0, stream>>>(qk, vt, cof + (size_t)l * P_, hb);
    gemm_mfma<2><<<g_p76, blk, 0, stream>>>(
        hb, wp, proj_b + (size_t)l * E_, xc, nullptr, nullptr, M, E_, E_);
    ln_block_kernel<<<B_ * S_, blk, 0, stream>>>(
        xc, hb, ln2_g + l * E_, ln2_b + l * E_, nullptr);
    gemm_mfma<1><<<g_fc1, blk, 0, stream>>>(
        hb, w1, fc1_b + (size_t)l * FF_, nullptr, fb, nullptr, M, FF_, E_);
    gemm_mfma<2><<<g_p76, blk, 0, stream>>>(
        fb, w2, fc2_b + (size_t)l * E_, xc, nullptr, nullptr, M, E_, FF_);
  }

  ln_post_kernel<<<B_, blk, 0, stream>>>(xc, ln_post_g, ln_post_b, out);
}